// Round 4
// baseline (398.121 us; speedup 1.0000x reference)
//
#include <hip/hip_runtime.h>
#include <math.h>

#define SUBS 20
#define TAPS 201
#define ENO 2000
#define INO 500
#define TDATA 20000

typedef __bf16 bf16x8 __attribute__((ext_vector_type(8)));
typedef float f32x4 __attribute__((ext_vector_type(4)));
typedef unsigned short ushort8 __attribute__((ext_vector_type(8)));

#define WGE_STRIDE 2048
#define WGI_STRIDE 512

// workspace byte offsets
#define WGE_OFF  0ull                    // ushort[64*2048] bf16 weights (E)
#define WGI_OFF  262144ull               // ushort[64*512]  bf16 weights (I)
#define KERN_OFF 327680ull               // float[40*201]   synapse kernels
#define INE_OFF  360448ull               // float[60*20000] filtered-input E
#define INI_OFF  (INE_OFF + 4800000ull)  // float[60*20000] filtered-input I
#define SYN_OFF  (INI_OFF + 4800000ull)  // float[60*20000] syn_in per (var,s)

__device__ __forceinline__ unsigned short f2bf(float f) {
  union { float f; unsigned int u; } c; c.f = f;
  unsigned int u = c.u;
  return (unsigned short)((u + 0x7FFFu + ((u >> 16) & 1u)) >> 16);  // RTNE
}

// ---------------------------------------------------------------------------
// K1: per-column prep (theta, hard/soft/softb) + kern filters + weight pads
// ---------------------------------------------------------------------------
__global__ __launch_bounds__(256) void prep_kernel(
    const float* __restrict__ u, const float* __restrict__ v,
    const float* __restrict__ C_log, const float* __restrict__ W_syn,
    const float* __restrict__ Tau_syn, const float* __restrict__ Delta_syn,
    float* __restrict__ out,
    unsigned short* __restrict__ wge, unsigned short* __restrict__ wgi,
    float* __restrict__ kern)
{
  if (blockIdx.x < 10) {
    const int n = blockIdx.x * 256 + threadIdx.x;
    if (n >= 2500) return;
    float x[SUBS], theta[SUBS], rebar[SUBS];
    float mx = -1e30f;
#pragma unroll
    for (int s = 0; s < SUBS; ++s) { x[s] = C_log[s*2500 + n]; mx = fmaxf(mx, x[s]); }
    float sum = 0.f;
#pragma unroll
    for (int s = 0; s < SUBS; ++s) { theta[s] = expf(x[s] - mx); sum += theta[s]; }
    const float inv = 1.f / sum;
    int idx = 0; float best = -1e30f;
#pragma unroll
    for (int s = 0; s < SUBS; ++s) {
      theta[s] *= inv;
      out[60000 + s*2500 + n] = theta[s];
      const float uu = u[s*2500 + n];
      const float r = logf(theta[s]) - logf(-logf(uu));
      rebar[s] = r;
      if (r > best) { best = r; idx = s; }   // first-wins strict >
    }
    const float lvk = logf(v[idx*2500 + n]);
#pragma unroll
    for (int s = 0; s < SUBS; ++s) {
      const float hz = (s == idx) ? 1.f : 0.f;
      const float sz = 1.f / (1.f + expf(-2.f * rebar[s])) + 1e-9f;
      const float vv = v[s*2500 + n];
      const float zb = (s == idx) ? (-logf(-logf(vv)))
                                  : (-logf(-logf(vv) / theta[s] - lvk));
      const float szb = 1.f / (1.f + expf(-2.f * zb)) + 1e-9f;
      out[110000 + s*2500 + n] = hz;
      out[160000 + s*2500 + n] = sz;
      out[210000 + s*2500 + n] = szb;
      if (n < ENO) {
        wge[(s     )*WGE_STRIDE + n] = f2bf(hz);
        wge[(20 + s)*WGE_STRIDE + n] = f2bf(sz);
        wge[(40 + s)*WGE_STRIDE + n] = f2bf(szb);
      } else {
        const int k = n - ENO;
        wgi[(s     )*WGI_STRIDE + k] = f2bf(hz);
        wgi[(20 + s)*WGI_STRIDE + k] = f2bf(sz);
        wgi[(40 + s)*WGI_STRIDE + k] = f2bf(szb);
      }
    }
  } else {
    const int tid = threadIdx.x;
    for (int i = tid; i < 40*TAPS; i += 256) {
      const int ch = i / TAPS, m = i - ch*TAPS;
      const float dl  = expf(Delta_syn[ch]);
      const float tau = expf(Tau_syn[ch]);
      const float t  = fmaxf((float)m - dl, 0.f);
      const float tt = t / tau;
      kern[i] = tt * expf(-tt) * W_syn[ch];
    }
    // zero the padded weight regions (ws is poisoned 0xAA every launch)
    for (int i = tid; i < 4*2048; i += 256) wge[(60 + (i >> 11))*WGE_STRIDE + (i & 2047)] = 0;
    for (int i = tid; i < 60*48;  i += 256) wge[(i / 48)*WGE_STRIDE + 2000 + (i % 48)] = 0;
    for (int i = tid; i < 4*512;  i += 256) wgi[(60 + (i >> 9))*WGI_STRIDE + (i & 511)] = 0;
    for (int i = tid; i < 60*12;  i += 256) wgi[(i / 12)*WGI_STRIDE + 500 + (i % 12)] = 0;
  }
}

// ---------------------------------------------------------------------------
// K2: LDS-free, barrier-free bf16 MFMA GEMM.
//     Each wave owns a 16-t tile, loads A/B fragments directly from global,
//     software-pipelined 1 step ahead (loads in flight across MFMA).
//     grid = (313 tiles-of-64t, 2: E/I), block = 256 (4 independent waves).
// ---------------------------------------------------------------------------
__global__ __launch_bounds__(256) void gemm_kernel(
    const float* __restrict__ S_e, const float* __restrict__ S_i,
    const unsigned short* __restrict__ wge, const unsigned short* __restrict__ wgi,
    float* __restrict__ in_e, float* __restrict__ in_i)
{
  const int tid  = threadIdx.x;
  const int wave = tid >> 6;
  const int lane = tid & 63;
  const int m16  = lane & 15;
  const int quad = lane >> 4;
  const int kq   = quad * 8;
  const int t0   = blockIdx.x * 64 + wave * 16;
  if (t0 >= TDATA) return;                    // wave-uniform; no barriers anywhere

  const bool isE = (blockIdx.y == 0);
  const float* S = isE ? S_e : S_i;
  const unsigned short* Wg = isE ? wge : wgi;
  float* outp = isE ? in_e : in_i;
  const int K       = isE ? ENO : INO;
  const int Wstride = isE ? WGE_STRIDE : WGI_STRIDE;
  const int steps   = isE ? 63 : 16;          // K padded to steps*32 with zero B

  const float* Arow = S + (size_t)(t0 + m16) * K;
  const unsigned short* Bp0 = Wg + (size_t)(     m16) * Wstride + kq;
  const unsigned short* Bp1 = Wg + (size_t)(16 + m16) * Wstride + kq;
  const unsigned short* Bp2 = Wg + (size_t)(32 + m16) * Wstride + kq;
  const unsigned short* Bp3 = Wg + (size_t)(48 + m16) * Wstride + kq;

  f32x4 acc0 = {0.f,0.f,0.f,0.f};
  f32x4 acc1 = acc0, acc2 = acc0, acc3 = acc0;

  // A-frag load, 4-granular clamp at the K tail. Clamped lanes read stale
  // in-bounds data; the matching B k-columns are zero-padded, so they
  // contribute 0 to the MFMA.
  auto ldA = [&](int k0, float4& lo, float4& hi) {
    const int kb  = k0 + kq;
    const int blo = (kb + 4 <= K) ? kb     : K - 4;
    const int bhi = (kb + 8 <= K) ? kb + 4 : K - 4;
    lo = *(const float4*)(Arow + blo);
    hi = *(const float4*)(Arow + bhi);
  };

  float4 alo, ahi;
  uint4 b0, b1, b2, b3;
  ldA(0, alo, ahi);
  b0 = *(const uint4*)(Bp0); b1 = *(const uint4*)(Bp1);
  b2 = *(const uint4*)(Bp2); b3 = *(const uint4*)(Bp3);

  for (int st = 0; st < steps; ++st) {
    // prefetch step st+1 (last iter re-loads st harmlessly; keeps code branch-free)
    const int kn = (st + 1 < steps) ? (st + 1) * 32 : st * 32;
    float4 nalo, nahi;
    ldA(kn, nalo, nahi);
    const uint4 nb0 = *(const uint4*)(Bp0 + kn);
    const uint4 nb1 = *(const uint4*)(Bp1 + kn);
    const uint4 nb2 = *(const uint4*)(Bp2 + kn);
    const uint4 nb3 = *(const uint4*)(Bp3 + kn);

    ushort8 ap;
    ap[0] = f2bf(alo.x); ap[1] = f2bf(alo.y); ap[2] = f2bf(alo.z); ap[3] = f2bf(alo.w);
    ap[4] = f2bf(ahi.x); ap[5] = f2bf(ahi.y); ap[6] = f2bf(ahi.z); ap[7] = f2bf(ahi.w);
    const bf16x8 af = *(const bf16x8*)&ap;
    acc0 = __builtin_amdgcn_mfma_f32_16x16x32_bf16(af, *(const bf16x8*)&b0, acc0, 0, 0, 0);
    acc1 = __builtin_amdgcn_mfma_f32_16x16x32_bf16(af, *(const bf16x8*)&b1, acc1, 0, 0, 0);
    acc2 = __builtin_amdgcn_mfma_f32_16x16x32_bf16(af, *(const bf16x8*)&b2, acc2, 0, 0, 0);
    acc3 = __builtin_amdgcn_mfma_f32_16x16x32_bf16(af, *(const bf16x8*)&b3, acc3, 0, 0, 0);
    alo = nalo; ahi = nahi; b0 = nb0; b1 = nb1; b2 = nb2; b3 = nb3;
  }

  // epilogue: C/D layout col=m16 -> c, row=quad*4+r -> t-local.
  // acc[0..3] = 4 consecutive t for one c -> float4 stores, no LDS.
  float* o = outp + t0 + quad * 4;
  *(float4*)(o + (size_t)(     m16) * TDATA) = *(float4*)&acc0;
  *(float4*)(o + (size_t)(16 + m16) * TDATA) = *(float4*)&acc1;
  *(float4*)(o + (size_t)(32 + m16) * TDATA) = *(float4*)&acc2;
  if (m16 < 12)
    *(float4*)(o + (size_t)(48 + m16) * TDATA) = *(float4*)&acc3;
}

// ---------------------------------------------------------------------------
// K3: 201-tap causal FIR per (var,s): syn = conv(IN_e,ke) + conv(IN_i,ki)
// ---------------------------------------------------------------------------
__device__ __forceinline__ int swz(int i) { return i + (i >> 5); }

__global__ __launch_bounds__(256) void conv_kernel(
    const float* __restrict__ in_e, const float* __restrict__ in_i,
    const float* __restrict__ kern, float* __restrict__ syn)
{
  __shared__ float Ee[2320];
  __shared__ float Ei[2320];
  const int ch = blockIdx.y;            // var*20 + s
  const int t0 = blockIdx.x * 2048;
  const int s  = ch % SUBS;
  const float* pe = in_e + (size_t)ch * TDATA;
  const float* pi = in_i + (size_t)ch * TDATA;
  for (int i = threadIdx.x; i < 2248; i += 256) {
    const int g = t0 - 200 + i;
    const bool ok = (g >= 0) && (g < TDATA);
    Ee[swz(i)] = ok ? pe[g] : 0.f;
    Ei[swz(i)] = ok ? pi[g] : 0.f;
  }
  __syncthreads();
  const float* ke = kern + (size_t)(s*2    ) * TAPS;
  const float* ki = kern + (size_t)(s*2 + 1) * TAPS;
  const int tb = threadIdx.x * 8;
  float acc[8] = {0.f,0.f,0.f,0.f,0.f,0.f,0.f,0.f};
  float we[8], wi[8];
#pragma unroll
  for (int j = 0; j < 8; ++j) {
    we[j] = Ee[swz(tb + 200 + j)];
    wi[j] = Ei[swz(tb + 200 + j)];
  }
#pragma unroll 8
  for (int m = 0; m < TAPS; ++m) {
    const float k0 = ke[m];
    const float k1 = ki[m];
#pragma unroll
    for (int j = 0; j < 8; ++j)
      acc[j] = fmaf(we[j], k0, fmaf(wi[j], k1, acc[j]));
    if (m < TAPS - 1) {
#pragma unroll
      for (int j = 7; j > 0; --j) { we[j] = we[j-1]; wi[j] = wi[j-1]; }
      we[0] = Ee[swz(tb + 199 - m)];
      wi[0] = Ei[swz(tb + 199 - m)];
    }
  }
  const int t = t0 + tb;
  if (t < TDATA) {
    float* o = syn + (size_t)ch * TDATA + t;
    *(float4*)(o    ) = make_float4(acc[0], acc[1], acc[2], acc[3]);
    *(float4*)(o + 4) = make_float4(acc[4], acc[5], acc[6], acc[7]);
  }
}

// ---------------------------------------------------------------------------
// K4: tanh tree combine -> V outputs
// ---------------------------------------------------------------------------
__global__ __launch_bounds__(256) void tree_kernel(
    const float* __restrict__ syn, const float* __restrict__ W_sub,
    const float* __restrict__ V_o, float* __restrict__ out)
{
  const int t = blockIdx.x * 256 + threadIdx.x;
  const int var = blockIdx.y;
  if (t >= TDATA) return;
  const float* sp = syn + (size_t)var * SUBS * TDATA + t;
  float so[SUBS];
#pragma unroll
  for (int s = SUBS - 1; s >= 0; --s) {
    float val = sp[(size_t)s * TDATA];
    const int c1 = 2*s + 1, c2 = 2*s + 2;
    if (c1 < SUBS) val += so[c1] * W_sub[c1];
    if (c2 < SUBS) val += so[c2] * W_sub[c2];
    so[s] = tanhf(val);
  }
  out[(size_t)var * TDATA + t] = so[0] * W_sub[0] + V_o[0];
}

extern "C" void kernel_launch(void* const* d_in, const int* in_sizes, int n_in,
                              void* d_out, int out_size, void* d_ws, size_t ws_size,
                              hipStream_t stream) {
  const float* S_e     = (const float*)d_in[0];
  const float* S_i     = (const float*)d_in[1];
  const float* u       = (const float*)d_in[2];
  const float* v       = (const float*)d_in[3];
  const float* W_syn   = (const float*)d_in[4];
  const float* Tau_syn = (const float*)d_in[5];
  const float* Delta   = (const float*)d_in[6];
  const float* W_sub   = (const float*)d_in[7];
  const float* V_o     = (const float*)d_in[8];
  const float* C_log   = (const float*)d_in[10];   // d_in[9] = Theta, unused
  float* out = (float*)d_out;
  char* ws = (char*)d_ws;
  unsigned short* wge = (unsigned short*)(ws + WGE_OFF);
  unsigned short* wgi = (unsigned short*)(ws + WGI_OFF);
  float* kern = (float*)(ws + KERN_OFF);
  float* in_e = (float*)(ws + INE_OFF);
  float* in_i = (float*)(ws + INI_OFF);
  float* syn  = (float*)(ws + SYN_OFF);

  prep_kernel<<<dim3(11), dim3(256), 0, stream>>>(u, v, C_log, W_syn, Tau_syn,
                                                  Delta, out, wge, wgi, kern);
  gemm_kernel<<<dim3(313, 2), dim3(256), 0, stream>>>(S_e, S_i, wge, wgi, in_e, in_i);
  conv_kernel<<<dim3(10, 60), dim3(256), 0, stream>>>(in_e, in_i, kern, syn);
  tree_kernel<<<dim3(79, 3), dim3(256), 0, stream>>>(syn, W_sub, V_o, out);
}

// Round 5
// 353.953 us; speedup vs baseline: 1.1248x; 1.1248x over previous
//
#include <hip/hip_runtime.h>
#include <math.h>

#define SUBS 20
#define TAPS 201
#define ENO 2000
#define INO 500
#define TDATA 20000

typedef __bf16 bf16x8 __attribute__((ext_vector_type(8)));
typedef float f32x4 __attribute__((ext_vector_type(4)));

#define WGE_STRIDE 2048
#define WGI_STRIDE 512

// workspace byte offsets (base layout — proven to fit)
#define WGE_OFF  0ull                    // ushort[64*2048] bf16 weights (E)
#define WGI_OFF  262144ull               // ushort[64*512]  bf16 weights (I)
#define KERN_OFF 327680ull               // float[40*201]   synapse kernels
#define INE_OFF  360448ull               // float[60*20000] filtered-input E
#define INI_OFF  (INE_OFF + 4800000ull)  // float[60*20000] filtered-input I
#define SYN_OFF  (INI_OFF + 4800000ull)  // float[60*20000] syn / E-partial P1
// extended split-K partials (used only when ws_size allows)
#define P2_OFF   (SYN_OFF + 4800000ull)
#define P3_OFF   (P2_OFF  + 4800000ull)
#define P4_OFF   (P3_OFF  + 4800000ull)
#define WS_BIG_NEED (P4_OFF + 4800000ull)   // 29,160,448 bytes

__device__ __forceinline__ unsigned short f2bf(float f) {
  union { float f; unsigned int u; } c; c.f = f;
  unsigned int u = c.u;
  return (unsigned short)((u + 0x7FFFu + ((u >> 16) & 1u)) >> 16);  // RTNE
}

// ---------------------------------------------------------------------------
// K1: per-column prep (theta, hard/soft/softb) + kern filters + weight pads
// ---------------------------------------------------------------------------
__global__ __launch_bounds__(256) void prep_kernel(
    const float* __restrict__ u, const float* __restrict__ v,
    const float* __restrict__ C_log, const float* __restrict__ W_syn,
    const float* __restrict__ Tau_syn, const float* __restrict__ Delta_syn,
    float* __restrict__ out,
    unsigned short* __restrict__ wge, unsigned short* __restrict__ wgi,
    float* __restrict__ kern)
{
  if (blockIdx.x < 10) {
    const int n = blockIdx.x * 256 + threadIdx.x;
    if (n >= 2500) return;
    float x[SUBS], theta[SUBS], rebar[SUBS];
    float mx = -1e30f;
#pragma unroll
    for (int s = 0; s < SUBS; ++s) { x[s] = C_log[s*2500 + n]; mx = fmaxf(mx, x[s]); }
    float sum = 0.f;
#pragma unroll
    for (int s = 0; s < SUBS; ++s) { theta[s] = expf(x[s] - mx); sum += theta[s]; }
    const float inv = 1.f / sum;
    int idx = 0; float best = -1e30f;
#pragma unroll
    for (int s = 0; s < SUBS; ++s) {
      theta[s] *= inv;
      out[60000 + s*2500 + n] = theta[s];
      const float uu = u[s*2500 + n];
      const float r = logf(theta[s]) - logf(-logf(uu));
      rebar[s] = r;
      if (r > best) { best = r; idx = s; }   // first-wins strict >
    }
    const float lvk = logf(v[idx*2500 + n]);
#pragma unroll
    for (int s = 0; s < SUBS; ++s) {
      const float hz = (s == idx) ? 1.f : 0.f;
      const float sz = 1.f / (1.f + expf(-2.f * rebar[s])) + 1e-9f;
      const float vv = v[s*2500 + n];
      const float zb = (s == idx) ? (-logf(-logf(vv)))
                                  : (-logf(-logf(vv) / theta[s] - lvk));
      const float szb = 1.f / (1.f + expf(-2.f * zb)) + 1e-9f;
      out[110000 + s*2500 + n] = hz;
      out[160000 + s*2500 + n] = sz;
      out[210000 + s*2500 + n] = szb;
      if (n < ENO) {
        wge[(s     )*WGE_STRIDE + n] = f2bf(hz);
        wge[(20 + s)*WGE_STRIDE + n] = f2bf(sz);
        wge[(40 + s)*WGE_STRIDE + n] = f2bf(szb);
      } else {
        const int k = n - ENO;
        wgi[(s     )*WGI_STRIDE + k] = f2bf(hz);
        wgi[(20 + s)*WGI_STRIDE + k] = f2bf(sz);
        wgi[(40 + s)*WGI_STRIDE + k] = f2bf(szb);
      }
    }
  } else {
    const int tid = threadIdx.x;
    for (int i = tid; i < 40*TAPS; i += 256) {
      const int ch = i / TAPS, m = i - ch*TAPS;
      const float dl  = expf(Delta_syn[ch]);
      const float tau = expf(Tau_syn[ch]);
      const float t  = fmaxf((float)m - dl, 0.f);
      const float tt = t / tau;
      kern[i] = tt * expf(-tt) * W_syn[ch];
    }
    // zero the padded weight regions (ws is poisoned 0xAA every launch)
    for (int i = tid; i < 4*2048; i += 256) wge[(60 + (i >> 11))*WGE_STRIDE + (i & 2047)] = 0;
    for (int i = tid; i < 60*48;  i += 256) wge[(i / 48)*WGE_STRIDE + 2000 + (i % 48)] = 0;
    for (int i = tid; i < 4*512;  i += 256) wgi[(60 + (i >> 9))*WGI_STRIDE + (i & 511)] = 0;
    for (int i = tid; i < 60*12;  i += 256) wgi[(i / 12)*WGI_STRIDE + 500 + (i % 12)] = 0;
  }
}

// ---------------------------------------------------------------------------
// K2: bf16 MFMA GEMM, split-K without atomics (R3 structure, deeper split).
//  mode=1 (big ws): y: 0..3 = E k-quarters -> {in_e,P1,P2,P3}; 4,5 = I halves
//                   -> {in_i,P4}
//  mode=0 (small):  y: 0,1 = E halves -> {in_e,P1}; 2 = I -> in_i
// ---------------------------------------------------------------------------
__global__ __launch_bounds__(256) void gemm_kernel(
    const float* __restrict__ S_e, const float* __restrict__ S_i,
    const unsigned short* __restrict__ wge, const unsigned short* __restrict__ wgi,
    float* __restrict__ in_e, float* __restrict__ in_i,
    float* __restrict__ P1, float* __restrict__ P2,
    float* __restrict__ P3, float* __restrict__ P4, const int mode)
{
  __shared__ unsigned short Alds[64*40];   // [t-row][k] bf16, stride 40 (pad)
  __shared__ unsigned short Blds[64*40];   // [c-row][k] bf16, stride 40
  const int tid  = threadIdx.x;
  const int t0   = blockIdx.x * 64;
  const int cy   = blockIdx.y;
  const int wave = tid >> 6;
  const int lane = tid & 63;
  const int m16  = lane & 15;
  const int quad = lane >> 4;
  const int slotA = tid & 7;   // float4 slot along k
  const int rowA  = tid >> 3;  // 32 rows/pass
  const int cB    = tid >> 2;
  const int slotB = tid & 3;

  bool isE; int k_base, steps; float* outp;
  if (mode) {
    isE = (cy < 4);
    if (isE) {
      k_base = cy * 512;
      steps  = (cy == 3) ? 15 : 16;          // chunk3: k[1536,2016), pad>2000
      outp   = (cy == 0) ? in_e : ((cy == 1) ? P1 : ((cy == 2) ? P2 : P3));
    } else {
      k_base = (cy == 4) ? 0 : 256;
      steps  = 8;                             // I: k[0,256),[256,512) pad>500
      outp   = (cy == 4) ? in_i : P4;
    }
  } else {
    isE = (cy < 2);
    if (isE) {
      k_base = cy * 1024;
      steps  = cy ? 31 : 32;
      outp   = cy ? P1 : in_e;
    } else {
      k_base = 0; steps = 16; outp = in_i;
    }
  }

  const float* S = isE ? S_e : S_i;
  const unsigned short* Wg = isE ? wge : wgi;
  const int K       = isE ? ENO : INO;
  const int Wstride = isE ? WGE_STRIDE : WGI_STRIDE;

  f32x4 acc0 = {0.f,0.f,0.f,0.f};
  f32x4 acc1 = acc0, acc2 = acc0, acc3 = acc0;

  for (int st = 0; st < steps; ++st) {
    const int k0 = k_base + st * 32;
#pragma unroll
    for (int p = 0; p < 2; ++p) {
      const int r = rowA + p*32;
      const int t = t0 + r;
      const int k = k0 + slotA*4;
      float4 val = make_float4(0.f, 0.f, 0.f, 0.f);
      if (t < TDATA) {
        if (k + 4 <= K) {
          val = *(const float4*)(S + (size_t)t*K + k);
        } else {
          val.x = (k+0 < K) ? S[(size_t)t*K + k+0] : 0.f;
          val.y = (k+1 < K) ? S[(size_t)t*K + k+1] : 0.f;
          val.z = (k+2 < K) ? S[(size_t)t*K + k+2] : 0.f;
          val.w = (k+3 < K) ? S[(size_t)t*K + k+3] : 0.f;
        }
      }
      ushort4 w4;
      w4.x = f2bf(val.x); w4.y = f2bf(val.y);
      w4.z = f2bf(val.z); w4.w = f2bf(val.w);
      *(ushort4*)(&Alds[r*40 + slotA*4]) = w4;
    }
    *(uint4*)(&Blds[cB*40 + slotB*8]) =
        *(const uint4*)(Wg + (size_t)cB*Wstride + k0 + slotB*8);
    __syncthreads();
    // frag: A[m=lane&15][k=quad*8+j], B[n=lane&15][k=quad*8+j]
    const bf16x8 a  = *(const bf16x8*)(&Alds[(wave*16 + m16)*40 + quad*8]);
    const bf16x8 b0 = *(const bf16x8*)(&Blds[(      m16)*40 + quad*8]);
    const bf16x8 b1 = *(const bf16x8*)(&Blds[(16 + m16)*40 + quad*8]);
    const bf16x8 b2 = *(const bf16x8*)(&Blds[(32 + m16)*40 + quad*8]);
    const bf16x8 b3 = *(const bf16x8*)(&Blds[(48 + m16)*40 + quad*8]);
    acc0 = __builtin_amdgcn_mfma_f32_16x16x32_bf16(a, b0, acc0, 0, 0, 0);
    acc1 = __builtin_amdgcn_mfma_f32_16x16x32_bf16(a, b1, acc1, 0, 0, 0);
    acc2 = __builtin_amdgcn_mfma_f32_16x16x32_bf16(a, b2, acc2, 0, 0, 0);
    acc3 = __builtin_amdgcn_mfma_f32_16x16x32_bf16(a, b3, acc3, 0, 0, 0);
    __syncthreads();
  }
  // epilogue: C/D layout col=m16 -> c, row=quad*4+r -> t-local.
  // acc[0..3] = 4 consecutive t for one c -> float4 stores, no LDS transpose.
  const int t = t0 + wave*16 + quad*4;
  if (t < TDATA) {
    float* o = outp + t;
    *(float4*)(o + (size_t)(     m16)*TDATA) = *(float4*)&acc0;
    *(float4*)(o + (size_t)(16 + m16)*TDATA) = *(float4*)&acc1;
    *(float4*)(o + (size_t)(32 + m16)*TDATA) = *(float4*)&acc2;
    if (m16 < 12)
      *(float4*)(o + (size_t)(48 + m16)*TDATA) = *(float4*)&acc3;
  }
}

// ---------------------------------------------------------------------------
// K2b: split-K reduction. mode=1: in_e += P1+P2+P3 ; in_i += P4
//      mode=0: in_e += P1
// ---------------------------------------------------------------------------
__global__ __launch_bounds__(256) void reduce_kernel(
    float* __restrict__ in_e, float* __restrict__ in_i,
    const float* __restrict__ P1, const float* __restrict__ P2,
    const float* __restrict__ P3, const float* __restrict__ P4, const int mode)
{
  const int n4 = 60 * TDATA / 4;   // 300000 float4
  if (mode && blockIdx.x >= 1172) {
    const int i = (blockIdx.x - 1172) * 256 + threadIdx.x;
    if (i < n4) {
      float4 a = ((const float4*)in_i)[i];
      const float4 p = ((const float4*)P4)[i];
      a.x += p.x; a.y += p.y; a.z += p.z; a.w += p.w;
      ((float4*)in_i)[i] = a;
    }
    return;
  }
  const int i = blockIdx.x * 256 + threadIdx.x;
  if (i < n4) {
    float4 a = ((const float4*)in_e)[i];
    const float4 p1 = ((const float4*)P1)[i];
    a.x += p1.x; a.y += p1.y; a.z += p1.z; a.w += p1.w;
    if (mode) {
      const float4 p2 = ((const float4*)P2)[i];
      const float4 p3 = ((const float4*)P3)[i];
      a.x += p2.x + p3.x; a.y += p2.y + p3.y;
      a.z += p2.z + p3.z; a.w += p2.w + p3.w;
    }
    ((float4*)in_e)[i] = a;
  }
}

// ---------------------------------------------------------------------------
// K3: 201-tap causal FIR per (var,s): syn = conv(IN_e,ke) + conv(IN_i,ki)
// ---------------------------------------------------------------------------
__device__ __forceinline__ int swz(int i) { return i + (i >> 5); }

__global__ __launch_bounds__(256) void conv_kernel(
    const float* __restrict__ in_e, const float* __restrict__ in_i,
    const float* __restrict__ kern, float* __restrict__ syn)
{
  __shared__ float Ee[2320];
  __shared__ float Ei[2320];
  const int ch = blockIdx.y;            // var*20 + s
  const int t0 = blockIdx.x * 2048;
  const int s  = ch % SUBS;
  const float* pe = in_e + (size_t)ch * TDATA;
  const float* pi = in_i + (size_t)ch * TDATA;
  for (int i = threadIdx.x; i < 2248; i += 256) {
    const int g = t0 - 200 + i;
    const bool ok = (g >= 0) && (g < TDATA);
    Ee[swz(i)] = ok ? pe[g] : 0.f;
    Ei[swz(i)] = ok ? pi[g] : 0.f;
  }
  __syncthreads();
  const float* ke = kern + (size_t)(s*2    ) * TAPS;
  const float* ki = kern + (size_t)(s*2 + 1) * TAPS;
  const int tb = threadIdx.x * 8;
  float acc[8] = {0.f,0.f,0.f,0.f,0.f,0.f,0.f,0.f};
  float we[8], wi[8];
#pragma unroll
  for (int j = 0; j < 8; ++j) {
    we[j] = Ee[swz(tb + 200 + j)];
    wi[j] = Ei[swz(tb + 200 + j)];
  }
#pragma unroll 8
  for (int m = 0; m < TAPS; ++m) {
    const float k0 = ke[m];
    const float k1 = ki[m];
#pragma unroll
    for (int j = 0; j < 8; ++j)
      acc[j] = fmaf(we[j], k0, fmaf(wi[j], k1, acc[j]));
    if (m < TAPS - 1) {
#pragma unroll
      for (int j = 7; j > 0; --j) { we[j] = we[j-1]; wi[j] = wi[j-1]; }
      we[0] = Ee[swz(tb + 199 - m)];
      wi[0] = Ei[swz(tb + 199 - m)];
    }
  }
  const int t = t0 + tb;
  if (t < TDATA) {
    float* o = syn + (size_t)ch * TDATA + t;
    *(float4*)(o    ) = make_float4(acc[0], acc[1], acc[2], acc[3]);
    *(float4*)(o + 4) = make_float4(acc[4], acc[5], acc[6], acc[7]);
  }
}

// ---------------------------------------------------------------------------
// K4: tanh tree combine -> V outputs
// ---------------------------------------------------------------------------
__global__ __launch_bounds__(256) void tree_kernel(
    const float* __restrict__ syn, const float* __restrict__ W_sub,
    const float* __restrict__ V_o, float* __restrict__ out)
{
  const int t = blockIdx.x * 256 + threadIdx.x;
  const int var = blockIdx.y;
  if (t >= TDATA) return;
  const float* sp = syn + (size_t)var * SUBS * TDATA + t;
  float so[SUBS];
#pragma unroll
  for (int s = SUBS - 1; s >= 0; --s) {
    float val = sp[(size_t)s * TDATA];
    const int c1 = 2*s + 1, c2 = 2*s + 2;
    if (c1 < SUBS) val += so[c1] * W_sub[c1];
    if (c2 < SUBS) val += so[c2] * W_sub[c2];
    so[s] = tanhf(val);
  }
  out[(size_t)var * TDATA + t] = so[0] * W_sub[0] + V_o[0];
}

extern "C" void kernel_launch(void* const* d_in, const int* in_sizes, int n_in,
                              void* d_out, int out_size, void* d_ws, size_t ws_size,
                              hipStream_t stream) {
  const float* S_e     = (const float*)d_in[0];
  const float* S_i     = (const float*)d_in[1];
  const float* u       = (const float*)d_in[2];
  const float* v       = (const float*)d_in[3];
  const float* W_syn   = (const float*)d_in[4];
  const float* Tau_syn = (const float*)d_in[5];
  const float* Delta   = (const float*)d_in[6];
  const float* W_sub   = (const float*)d_in[7];
  const float* V_o     = (const float*)d_in[8];
  const float* C_log   = (const float*)d_in[10];   // d_in[9] = Theta, unused
  float* out = (float*)d_out;
  char* ws = (char*)d_ws;
  unsigned short* wge = (unsigned short*)(ws + WGE_OFF);
  unsigned short* wgi = (unsigned short*)(ws + WGI_OFF);
  float* kern = (float*)(ws + KERN_OFF);
  float* in_e = (float*)(ws + INE_OFF);
  float* in_i = (float*)(ws + INI_OFF);
  float* syn  = (float*)(ws + SYN_OFF);   // doubles as E-partial P1 before conv
  float* P1   = syn;
  float* P2   = (float*)(ws + P2_OFF);
  float* P3   = (float*)(ws + P3_OFF);
  float* P4   = (float*)(ws + P4_OFF);

  // ws_size is constant across calls -> deterministic path, graph-safe.
  const int mode = (ws_size >= WS_BIG_NEED) ? 1 : 0;

  prep_kernel<<<dim3(11), dim3(256), 0, stream>>>(u, v, C_log, W_syn, Tau_syn,
                                                  Delta, out, wge, wgi, kern);
  gemm_kernel<<<dim3(313, mode ? 6 : 3), dim3(256), 0, stream>>>(
      S_e, S_i, wge, wgi, in_e, in_i, P1, P2, P3, P4, mode);
  reduce_kernel<<<dim3(mode ? 2344 : 1172), dim3(256), 0, stream>>>(
      in_e, in_i, P1, P2, P3, P4, mode);
  conv_kernel<<<dim3(10, 60), dim3(256), 0, stream>>>(in_e, in_i, kern, syn);
  tree_kernel<<<dim3(79, 3), dim3(256), 0, stream>>>(syn, W_sub, V_o, out);
}

// Round 6
// 345.534 us; speedup vs baseline: 1.1522x; 1.0244x over previous
//
#include <hip/hip_runtime.h>
#include <math.h>

#define SUBS 20
#define TAPS 201
#define ENO 2000
#define INO 500
#define TDATA 20000

typedef __bf16 bf16x8 __attribute__((ext_vector_type(8)));
typedef float f32x4 __attribute__((ext_vector_type(4)));

#define WGE_STRIDE 2048
#define WGI_STRIDE 512

// workspace byte offsets (ws >= 29,160,448 proven by R5 mode-1 pass)
#define WGE_OFF  0ull                    // ushort[64*2048] bf16 weights (E)
#define WGI_OFF  262144ull               // ushort[64*512]  bf16 weights (I)
#define KERN_OFF 327680ull               // float[40*201]   synapse kernels
#define INE_OFF  360448ull               // float[60*20000] filtered-input E
#define INI_OFF  (INE_OFF + 4800000ull)  // float[60*20000] filtered-input I
#define SYN_OFF  (INI_OFF + 4800000ull)  // float[60*20000] syn / E-partial P1
#define P2_OFF   (SYN_OFF + 4800000ull)
#define P3_OFF   (P2_OFF  + 4800000ull)
#define P4_OFF   (P3_OFF  + 4800000ull)

__device__ __forceinline__ unsigned short f2bf(float f) {
  union { float f; unsigned int u; } c; c.f = f;
  unsigned int u = c.u;
  return (unsigned short)((u + 0x7FFFu + ((u >> 16) & 1u)) >> 16);  // RTNE
}

// ---------------------------------------------------------------------------
// K1: per-column prep (theta, hard/soft/softb) + kern filters + weight pads
// ---------------------------------------------------------------------------
__global__ __launch_bounds__(256) void prep_kernel(
    const float* __restrict__ u, const float* __restrict__ v,
    const float* __restrict__ C_log, const float* __restrict__ W_syn,
    const float* __restrict__ Tau_syn, const float* __restrict__ Delta_syn,
    float* __restrict__ out,
    unsigned short* __restrict__ wge, unsigned short* __restrict__ wgi,
    float* __restrict__ kern)
{
  if (blockIdx.x < 10) {
    const int n = blockIdx.x * 256 + threadIdx.x;
    if (n >= 2500) return;
    float x[SUBS], theta[SUBS], rebar[SUBS];
    float mx = -1e30f;
#pragma unroll
    for (int s = 0; s < SUBS; ++s) { x[s] = C_log[s*2500 + n]; mx = fmaxf(mx, x[s]); }
    float sum = 0.f;
#pragma unroll
    for (int s = 0; s < SUBS; ++s) { theta[s] = expf(x[s] - mx); sum += theta[s]; }
    const float inv = 1.f / sum;
    int idx = 0; float best = -1e30f;
#pragma unroll
    for (int s = 0; s < SUBS; ++s) {
      theta[s] *= inv;
      out[60000 + s*2500 + n] = theta[s];
      const float uu = u[s*2500 + n];
      const float r = logf(theta[s]) - logf(-logf(uu));
      rebar[s] = r;
      if (r > best) { best = r; idx = s; }   // first-wins strict >
    }
    const float lvk = logf(v[idx*2500 + n]);
#pragma unroll
    for (int s = 0; s < SUBS; ++s) {
      const float hz = (s == idx) ? 1.f : 0.f;
      const float sz = 1.f / (1.f + expf(-2.f * rebar[s])) + 1e-9f;
      const float vv = v[s*2500 + n];
      const float zb = (s == idx) ? (-logf(-logf(vv)))
                                  : (-logf(-logf(vv) / theta[s] - lvk));
      const float szb = 1.f / (1.f + expf(-2.f * zb)) + 1e-9f;
      out[110000 + s*2500 + n] = hz;
      out[160000 + s*2500 + n] = sz;
      out[210000 + s*2500 + n] = szb;
      if (n < ENO) {
        wge[(s     )*WGE_STRIDE + n] = f2bf(hz);
        wge[(20 + s)*WGE_STRIDE + n] = f2bf(sz);
        wge[(40 + s)*WGE_STRIDE + n] = f2bf(szb);
      } else {
        const int k = n - ENO;
        wgi[(s     )*WGI_STRIDE + k] = f2bf(hz);
        wgi[(20 + s)*WGI_STRIDE + k] = f2bf(sz);
        wgi[(40 + s)*WGI_STRIDE + k] = f2bf(szb);
      }
    }
  } else {
    const int tid = threadIdx.x;
    for (int i = tid; i < 40*TAPS; i += 256) {
      const int ch = i / TAPS, m = i - ch*TAPS;
      const float dl  = expf(Delta_syn[ch]);
      const float tau = expf(Tau_syn[ch]);
      const float t  = fmaxf((float)m - dl, 0.f);
      const float tt = t / tau;
      kern[i] = tt * expf(-tt) * W_syn[ch];
    }
    // zero the padded weight regions (ws is poisoned 0xAA every launch)
    for (int i = tid; i < 4*2048; i += 256) wge[(60 + (i >> 11))*WGE_STRIDE + (i & 2047)] = 0;
    for (int i = tid; i < 60*48;  i += 256) wge[(i / 48)*WGE_STRIDE + 2000 + (i % 48)] = 0;
    for (int i = tid; i < 4*512;  i += 256) wgi[(60 + (i >> 9))*WGI_STRIDE + (i & 511)] = 0;
    for (int i = tid; i < 60*12;  i += 256) wgi[(i / 12)*WGI_STRIDE + 500 + (i % 12)] = 0;
  }
}

// ---------------------------------------------------------------------------
// K2: bf16 MFMA GEMM, M=128 / BK=64 / 512 threads (8 waves), split-K.
//     grid = (157, 6); y: 0..3 = E k-quarters -> {in_e,P1,P2,P3};
//                      4,5 = I k-halves -> {in_i,P4}
//     Fatter steps amortize the ~6000-cyc per-step latency (R1-R5 model).
// ---------------------------------------------------------------------------
__global__ __launch_bounds__(512) void gemm_kernel(
    const float* __restrict__ S_e, const float* __restrict__ S_i,
    const unsigned short* __restrict__ wge, const unsigned short* __restrict__ wgi,
    float* __restrict__ in_e, float* __restrict__ in_i,
    float* __restrict__ P1, float* __restrict__ P2,
    float* __restrict__ P3, float* __restrict__ P4)
{
  __shared__ unsigned short Alds[128*72];  // [t-row][k] bf16, stride 72
  __shared__ unsigned short Blds[64*72];   // [c-row][k] bf16, stride 72
  const int tid  = threadIdx.x;
  const int wave = tid >> 6;
  const int lane = tid & 63;
  const int m16  = lane & 15;
  const int quad = lane >> 4;
  const int t0   = blockIdx.x * 128;
  const int cy   = blockIdx.y;
  const bool isE = (cy < 4);

  const float* S = isE ? S_e : S_i;
  const unsigned short* Wg = isE ? wge : wgi;
  float* outp = (cy == 0) ? in_e : (cy == 1) ? P1 : (cy == 2) ? P2
              : (cy == 3) ? P3   : (cy == 4) ? in_i : P4;
  const int K       = isE ? ENO : INO;
  const int Wstride = isE ? WGE_STRIDE : WGI_STRIDE;
  const int k_base  = isE ? cy * 512 : (cy - 4) * 256;
  const int steps   = isE ? 8 : 4;     // B rows zero-padded past K

  // staging maps
  const int rowA  = tid >> 2;          // 0..127
  const int slotA = tid & 3;           // 16 floats at k0 + slotA*16
  const int rowB  = tid >> 3;          // 0..63
  const int slotB = tid & 7;           // 8 shorts at k0 + slotB*8
  const int tA    = t0 + rowA;
  const float* Arow = S + (size_t)((tA < TDATA) ? tA : TDATA - 1) * K;
  const unsigned short* Brow = Wg + (size_t)rowB * Wstride;

  f32x4 acc0 = {0.f,0.f,0.f,0.f};
  f32x4 acc1 = acc0, acc2 = acc0, acc3 = acc0;

  for (int st = 0; st < steps; ++st) {
    const int k0 = k_base + st * 64;
    // B stage first so its latency overlaps the A converts
    const uint4 bw = *(const uint4*)(Brow + k0 + slotB*8);
    float4 v0, v1, v2, v3;
    {
      const int kb = k0 + slotA*16;
      // 4-granular clamp at K tail: stale A data x zero-padded B = 0
      const int c0 = (kb +  4 <= K) ? kb      : K - 4;
      const int c1 = (kb +  8 <= K) ? kb +  4 : K - 4;
      const int c2 = (kb + 12 <= K) ? kb +  8 : K - 4;
      const int c3 = (kb + 16 <= K) ? kb + 12 : K - 4;
      v0 = *(const float4*)(Arow + c0);
      v1 = *(const float4*)(Arow + c1);
      v2 = *(const float4*)(Arow + c2);
      v3 = *(const float4*)(Arow + c3);
    }
    ushort4 p0, p1, p2, p3;
    p0.x = f2bf(v0.x); p0.y = f2bf(v0.y); p0.z = f2bf(v0.z); p0.w = f2bf(v0.w);
    p1.x = f2bf(v1.x); p1.y = f2bf(v1.y); p1.z = f2bf(v1.z); p1.w = f2bf(v1.w);
    p2.x = f2bf(v2.x); p2.y = f2bf(v2.y); p2.z = f2bf(v2.z); p2.w = f2bf(v2.w);
    p3.x = f2bf(v3.x); p3.y = f2bf(v3.y); p3.z = f2bf(v3.z); p3.w = f2bf(v3.w);
    unsigned short* adst = &Alds[rowA*72 + slotA*16];
    *(ushort4*)(adst    ) = p0;  *(ushort4*)(adst + 4) = p1;
    *(ushort4*)(adst + 8) = p2;  *(ushort4*)(adst +12) = p3;
    *(uint4*)(&Blds[rowB*72 + slotB*8]) = bw;
    __syncthreads();
    // compute: 2 k-halves of 32; frag A[m=lane&15][k=quad*8+j]
#pragma unroll
    for (int h = 0; h < 2; ++h) {
      const int kh = h*32 + quad*8;
      const bf16x8 a  = *(const bf16x8*)(&Alds[(wave*16 + m16)*72 + kh]);
      const bf16x8 b0 = *(const bf16x8*)(&Blds[(      m16)*72 + kh]);
      const bf16x8 b1 = *(const bf16x8*)(&Blds[(16 + m16)*72 + kh]);
      const bf16x8 b2 = *(const bf16x8*)(&Blds[(32 + m16)*72 + kh]);
      const bf16x8 b3 = *(const bf16x8*)(&Blds[(48 + m16)*72 + kh]);
      acc0 = __builtin_amdgcn_mfma_f32_16x16x32_bf16(a, b0, acc0, 0, 0, 0);
      acc1 = __builtin_amdgcn_mfma_f32_16x16x32_bf16(a, b1, acc1, 0, 0, 0);
      acc2 = __builtin_amdgcn_mfma_f32_16x16x32_bf16(a, b2, acc2, 0, 0, 0);
      acc3 = __builtin_amdgcn_mfma_f32_16x16x32_bf16(a, b3, acc3, 0, 0, 0);
    }
    __syncthreads();
  }
  // epilogue: C/D layout col=m16 -> c, row=quad*4+r -> t-local (within wave's 16)
  const int t = t0 + wave*16 + quad*4;
  if (t < TDATA) {
    float* o = outp + t;
    *(float4*)(o + (size_t)(     m16)*TDATA) = *(float4*)&acc0;
    *(float4*)(o + (size_t)(16 + m16)*TDATA) = *(float4*)&acc1;
    *(float4*)(o + (size_t)(32 + m16)*TDATA) = *(float4*)&acc2;
    if (m16 < 12)
      *(float4*)(o + (size_t)(48 + m16)*TDATA) = *(float4*)&acc3;
  }
}

// ---------------------------------------------------------------------------
// K2b: split-K reduction: in_e += P1+P2+P3 ; in_i += P4
// ---------------------------------------------------------------------------
__global__ __launch_bounds__(256) void reduce_kernel(
    float* __restrict__ in_e, float* __restrict__ in_i,
    const float* __restrict__ P1, const float* __restrict__ P2,
    const float* __restrict__ P3, const float* __restrict__ P4)
{
  const int n4 = 60 * TDATA / 4;   // 300000 float4
  if (blockIdx.x >= 1172) {
    const int i = (blockIdx.x - 1172) * 256 + threadIdx.x;
    if (i < n4) {
      float4 a = ((const float4*)in_i)[i];
      const float4 p = ((const float4*)P4)[i];
      a.x += p.x; a.y += p.y; a.z += p.z; a.w += p.w;
      ((float4*)in_i)[i] = a;
    }
    return;
  }
  const int i = blockIdx.x * 256 + threadIdx.x;
  if (i < n4) {
    float4 a = ((const float4*)in_e)[i];
    const float4 p1 = ((const float4*)P1)[i];
    const float4 p2 = ((const float4*)P2)[i];
    const float4 p3 = ((const float4*)P3)[i];
    a.x += p1.x + p2.x + p3.x; a.y += p1.y + p2.y + p3.y;
    a.z += p1.z + p2.z + p3.z; a.w += p1.w + p2.w + p3.w;
    ((float4*)in_e)[i] = a;
  }
}

// ---------------------------------------------------------------------------
// K3: 201-tap causal FIR per (var,s): syn = conv(IN_e,ke) + conv(IN_i,ki)
// ---------------------------------------------------------------------------
__device__ __forceinline__ int swz(int i) { return i + (i >> 5); }

__global__ __launch_bounds__(256) void conv_kernel(
    const float* __restrict__ in_e, const float* __restrict__ in_i,
    const float* __restrict__ kern, float* __restrict__ syn)
{
  __shared__ float Ee[2320];
  __shared__ float Ei[2320];
  const int ch = blockIdx.y;            // var*20 + s
  const int t0 = blockIdx.x * 2048;
  const int s  = ch % SUBS;
  const float* pe = in_e + (size_t)ch * TDATA;
  const float* pi = in_i + (size_t)ch * TDATA;
  for (int i = threadIdx.x; i < 2248; i += 256) {
    const int g = t0 - 200 + i;
    const bool ok = (g >= 0) && (g < TDATA);
    Ee[swz(i)] = ok ? pe[g] : 0.f;
    Ei[swz(i)] = ok ? pi[g] : 0.f;
  }
  __syncthreads();
  const float* ke = kern + (size_t)(s*2    ) * TAPS;
  const float* ki = kern + (size_t)(s*2 + 1) * TAPS;
  const int tb = threadIdx.x * 8;
  float acc[8] = {0.f,0.f,0.f,0.f,0.f,0.f,0.f,0.f};
  float we[8], wi[8];
#pragma unroll
  for (int j = 0; j < 8; ++j) {
    we[j] = Ee[swz(tb + 200 + j)];
    wi[j] = Ei[swz(tb + 200 + j)];
  }
#pragma unroll 8
  for (int m = 0; m < TAPS; ++m) {
    const float k0 = ke[m];
    const float k1 = ki[m];
#pragma unroll
    for (int j = 0; j < 8; ++j)
      acc[j] = fmaf(we[j], k0, fmaf(wi[j], k1, acc[j]));
    if (m < TAPS - 1) {
#pragma unroll
      for (int j = 7; j > 0; --j) { we[j] = we[j-1]; wi[j] = wi[j-1]; }
      we[0] = Ee[swz(tb + 199 - m)];
      wi[0] = Ei[swz(tb + 199 - m)];
    }
  }
  const int t = t0 + tb;
  if (t < TDATA) {
    float* o = syn + (size_t)ch * TDATA + t;
    *(float4*)(o    ) = make_float4(acc[0], acc[1], acc[2], acc[3]);
    *(float4*)(o + 4) = make_float4(acc[4], acc[5], acc[6], acc[7]);
  }
}

// ---------------------------------------------------------------------------
// K4: tanh tree combine -> V outputs
// ---------------------------------------------------------------------------
__global__ __launch_bounds__(256) void tree_kernel(
    const float* __restrict__ syn, const float* __restrict__ W_sub,
    const float* __restrict__ V_o, float* __restrict__ out)
{
  const int t = blockIdx.x * 256 + threadIdx.x;
  const int var = blockIdx.y;
  if (t >= TDATA) return;
  const float* sp = syn + (size_t)var * SUBS * TDATA + t;
  float so[SUBS];
#pragma unroll
  for (int s = SUBS - 1; s >= 0; --s) {
    float val = sp[(size_t)s * TDATA];
    const int c1 = 2*s + 1, c2 = 2*s + 2;
    if (c1 < SUBS) val += so[c1] * W_sub[c1];
    if (c2 < SUBS) val += so[c2] * W_sub[c2];
    so[s] = tanhf(val);
  }
  out[(size_t)var * TDATA + t] = so[0] * W_sub[0] + V_o[0];
}

extern "C" void kernel_launch(void* const* d_in, const int* in_sizes, int n_in,
                              void* d_out, int out_size, void* d_ws, size_t ws_size,
                              hipStream_t stream) {
  const float* S_e     = (const float*)d_in[0];
  const float* S_i     = (const float*)d_in[1];
  const float* u       = (const float*)d_in[2];
  const float* v       = (const float*)d_in[3];
  const float* W_syn   = (const float*)d_in[4];
  const float* Tau_syn = (const float*)d_in[5];
  const float* Delta   = (const float*)d_in[6];
  const float* W_sub   = (const float*)d_in[7];
  const float* V_o     = (const float*)d_in[8];
  const float* C_log   = (const float*)d_in[10];   // d_in[9] = Theta, unused
  float* out = (float*)d_out;
  char* ws = (char*)d_ws;
  unsigned short* wge = (unsigned short*)(ws + WGE_OFF);
  unsigned short* wgi = (unsigned short*)(ws + WGI_OFF);
  float* kern = (float*)(ws + KERN_OFF);
  float* in_e = (float*)(ws + INE_OFF);
  float* in_i = (float*)(ws + INI_OFF);
  float* syn  = (float*)(ws + SYN_OFF);   // doubles as E-partial P1 before conv
  float* P1   = syn;
  float* P2   = (float*)(ws + P2_OFF);
  float* P3   = (float*)(ws + P3_OFF);
  float* P4   = (float*)(ws + P4_OFF);

  prep_kernel<<<dim3(11), dim3(256), 0, stream>>>(u, v, C_log, W_syn, Tau_syn,
                                                  Delta, out, wge, wgi, kern);
  gemm_kernel<<<dim3(157, 6), dim3(512), 0, stream>>>(
      S_e, S_i, wge, wgi, in_e, in_i, P1, P2, P3, P4);
  reduce_kernel<<<dim3(2344), dim3(256), 0, stream>>>(in_e, in_i, P1, P2, P3, P4);
  conv_kernel<<<dim3(10, 60), dim3(256), 0, stream>>>(in_e, in_i, kern, syn);
  tree_kernel<<<dim3(79, 3), dim3(256), 0, stream>>>(syn, W_sub, V_o, out);
}

// Round 7
// 337.207 us; speedup vs baseline: 1.1806x; 1.0247x over previous
//
#include <hip/hip_runtime.h>
#include <math.h>

#define SUBS 20
#define TAPS 201
#define ENO 2000
#define INO 500
#define TDATA 20000

typedef __bf16 bf16x8 __attribute__((ext_vector_type(8)));
typedef float f32x4 __attribute__((ext_vector_type(4)));

#define WGE_STRIDE 2048
#define WGI_STRIDE 512

// workspace byte offsets (ws is ~640 MB per R6 fill counter; 29.2 MB used)
#define WGE_OFF  0ull                    // ushort[64*2048] bf16 weights (E)
#define WGI_OFF  262144ull               // ushort[64*512]  bf16 weights (I)
#define KERN_OFF 327680ull               // float[40*201]   synapse kernels
#define INE_OFF  360448ull               // float[60*20000] E partial chunk0
#define INI_OFF  (INE_OFF + 4800000ull)  // float[60*20000] I (full K)
#define P1_OFF   (INI_OFF + 4800000ull)  // float[60*20000] E partial chunk1
#define P2_OFF   (P1_OFF  + 4800000ull)  // float[60*20000] E partial chunk2
#define P3_OFF   (P2_OFF  + 4800000ull)  // float[60*20000] E partial chunk3
#define SYN_OFF  (P3_OFF  + 4800000ull)  // float[60*20000] syn_in (no alias)

__device__ __forceinline__ unsigned short f2bf(float f) {
  union { float f; unsigned int u; } c; c.f = f;
  unsigned int u = c.u;
  return (unsigned short)((u + 0x7FFFu + ((u >> 16) & 1u)) >> 16);  // RTNE
}

__device__ __forceinline__ float fast_tanh(float x) {
  const float ax = fabsf(x);
  const float e  = __expf(2.f * ax);     // e=inf -> t=1 (saturation) is exact
  const float t  = 1.f - 2.f / (e + 1.f);
  return copysignf(t, x);
}

// ---------------------------------------------------------------------------
// K1: per-column prep (theta, hard/soft/softb) + kern filters + weight pads
// ---------------------------------------------------------------------------
__global__ __launch_bounds__(256) void prep_kernel(
    const float* __restrict__ u, const float* __restrict__ v,
    const float* __restrict__ C_log, const float* __restrict__ W_syn,
    const float* __restrict__ Tau_syn, const float* __restrict__ Delta_syn,
    float* __restrict__ out,
    unsigned short* __restrict__ wge, unsigned short* __restrict__ wgi,
    float* __restrict__ kern)
{
  if (blockIdx.x < 10) {
    const int n = blockIdx.x * 256 + threadIdx.x;
    if (n >= 2500) return;
    float x[SUBS], theta[SUBS], rebar[SUBS];
    float mx = -1e30f;
#pragma unroll
    for (int s = 0; s < SUBS; ++s) { x[s] = C_log[s*2500 + n]; mx = fmaxf(mx, x[s]); }
    float sum = 0.f;
#pragma unroll
    for (int s = 0; s < SUBS; ++s) { theta[s] = __expf(x[s] - mx); sum += theta[s]; }
    const float inv = 1.f / sum;
    int idx = 0; float best = -1e30f;
#pragma unroll
    for (int s = 0; s < SUBS; ++s) {
      theta[s] *= inv;
      out[60000 + s*2500 + n] = theta[s];
      const float uu = u[s*2500 + n];
      const float r = __logf(theta[s]) - __logf(-__logf(uu));
      rebar[s] = r;
      if (r > best) { best = r; idx = s; }   // first-wins strict >
    }
    const float lvk = __logf(v[idx*2500 + n]);
#pragma unroll
    for (int s = 0; s < SUBS; ++s) {
      const float hz = (s == idx) ? 1.f : 0.f;
      const float sz = 1.f / (1.f + __expf(-2.f * rebar[s])) + 1e-9f;
      const float vv = v[s*2500 + n];
      const float zb = (s == idx) ? (-__logf(-__logf(vv)))
                                  : (-__logf(-__logf(vv) / theta[s] - lvk));
      const float szb = 1.f / (1.f + __expf(-2.f * zb)) + 1e-9f;
      out[110000 + s*2500 + n] = hz;
      out[160000 + s*2500 + n] = sz;
      out[210000 + s*2500 + n] = szb;
      if (n < ENO) {
        wge[(s     )*WGE_STRIDE + n] = f2bf(hz);
        wge[(20 + s)*WGE_STRIDE + n] = f2bf(sz);
        wge[(40 + s)*WGE_STRIDE + n] = f2bf(szb);
      } else {
        const int k = n - ENO;
        wgi[(s     )*WGI_STRIDE + k] = f2bf(hz);
        wgi[(20 + s)*WGI_STRIDE + k] = f2bf(sz);
        wgi[(40 + s)*WGI_STRIDE + k] = f2bf(szb);
      }
    }
  } else {
    const int tid = threadIdx.x;
    for (int i = tid; i < 40*TAPS; i += 256) {
      const int ch = i / TAPS, m = i - ch*TAPS;
      const float dl  = __expf(Delta_syn[ch]);
      const float tau = __expf(Tau_syn[ch]);
      const float t  = fmaxf((float)m - dl, 0.f);
      const float tt = t / tau;
      kern[i] = tt * __expf(-tt) * W_syn[ch];
    }
    // zero the padded weight regions (ws is poisoned 0xAA every launch)
    for (int i = tid; i < 4*2048; i += 256) wge[(60 + (i >> 11))*WGE_STRIDE + (i & 2047)] = 0;
    for (int i = tid; i < 60*48;  i += 256) wge[(i / 48)*WGE_STRIDE + 2000 + (i % 48)] = 0;
    for (int i = tid; i < 4*512;  i += 256) wgi[(60 + (i >> 9))*WGI_STRIDE + (i & 511)] = 0;
    for (int i = tid; i < 60*12;  i += 256) wgi[(i / 12)*WGI_STRIDE + 500 + (i % 12)] = 0;
  }
}

// ---------------------------------------------------------------------------
// K2: bf16 MFMA GEMM, M=128 / BK=64 / 512 threads (8 waves), split-K E-only.
//     grid = (157, 5); y: 0..3 = E k-quarters -> {in_e,P1,P2,P3}; 4 = I full.
//     Partial reduction is folded into conv's staging (no reduce dispatch).
// ---------------------------------------------------------------------------
__global__ __launch_bounds__(512) void gemm_kernel(
    const float* __restrict__ S_e, const float* __restrict__ S_i,
    const unsigned short* __restrict__ wge, const unsigned short* __restrict__ wgi,
    float* __restrict__ in_e, float* __restrict__ in_i,
    float* __restrict__ P1, float* __restrict__ P2, float* __restrict__ P3)
{
  __shared__ unsigned short Alds[128*72];  // [t-row][k] bf16, stride 72
  __shared__ unsigned short Blds[64*72];   // [c-row][k] bf16, stride 72
  const int tid  = threadIdx.x;
  const int wave = tid >> 6;
  const int lane = tid & 63;
  const int m16  = lane & 15;
  const int quad = lane >> 4;
  const int t0   = blockIdx.x * 128;
  const int cy   = blockIdx.y;
  const bool isE = (cy < 4);

  const float* S = isE ? S_e : S_i;
  const unsigned short* Wg = isE ? wge : wgi;
  float* outp = (cy == 0) ? in_e : (cy == 1) ? P1 : (cy == 2) ? P2
              : (cy == 3) ? P3   : in_i;
  const int K       = isE ? ENO : INO;
  const int Wstride = isE ? WGE_STRIDE : WGI_STRIDE;
  const int k_base  = isE ? cy * 512 : 0;
  const int steps   = 8;               // E: 512-span quarters; I: 512 (pad>500)

  // staging maps
  const int rowA  = tid >> 2;          // 0..127
  const int slotA = tid & 3;           // 16 floats at k0 + slotA*16
  const int rowB  = tid >> 3;          // 0..63
  const int slotB = tid & 7;           // 8 shorts at k0 + slotB*8
  const int tA    = t0 + rowA;
  const float* Arow = S + (size_t)((tA < TDATA) ? tA : TDATA - 1) * K;
  const unsigned short* Brow = Wg + (size_t)rowB * Wstride;

  f32x4 acc0 = {0.f,0.f,0.f,0.f};
  f32x4 acc1 = acc0, acc2 = acc0, acc3 = acc0;

  for (int st = 0; st < steps; ++st) {
    const int k0 = k_base + st * 64;
    // B stage first so its latency overlaps the A converts
    const uint4 bw = *(const uint4*)(Brow + k0 + slotB*8);
    float4 v0, v1, v2, v3;
    {
      const int kb = k0 + slotA*16;
      // 4-granular clamp at K tail: stale A data x zero-padded B = 0
      const int c0 = (kb +  4 <= K) ? kb      : K - 4;
      const int c1 = (kb +  8 <= K) ? kb +  4 : K - 4;
      const int c2 = (kb + 12 <= K) ? kb +  8 : K - 4;
      const int c3 = (kb + 16 <= K) ? kb + 12 : K - 4;
      v0 = *(const float4*)(Arow + c0);
      v1 = *(const float4*)(Arow + c1);
      v2 = *(const float4*)(Arow + c2);
      v3 = *(const float4*)(Arow + c3);
    }
    ushort4 p0, p1, p2, p3;
    p0.x = f2bf(v0.x); p0.y = f2bf(v0.y); p0.z = f2bf(v0.z); p0.w = f2bf(v0.w);
    p1.x = f2bf(v1.x); p1.y = f2bf(v1.y); p1.z = f2bf(v1.z); p1.w = f2bf(v1.w);
    p2.x = f2bf(v2.x); p2.y = f2bf(v2.y); p2.z = f2bf(v2.z); p2.w = f2bf(v2.w);
    p3.x = f2bf(v3.x); p3.y = f2bf(v3.y); p3.z = f2bf(v3.z); p3.w = f2bf(v3.w);
    unsigned short* adst = &Alds[rowA*72 + slotA*16];
    *(ushort4*)(adst    ) = p0;  *(ushort4*)(adst + 4) = p1;
    *(ushort4*)(adst + 8) = p2;  *(ushort4*)(adst +12) = p3;
    *(uint4*)(&Blds[rowB*72 + slotB*8]) = bw;
    __syncthreads();
    // compute: 2 k-halves of 32; frag A[m=lane&15][k=quad*8+j]
#pragma unroll
    for (int h = 0; h < 2; ++h) {
      const int kh = h*32 + quad*8;
      const bf16x8 a  = *(const bf16x8*)(&Alds[(wave*16 + m16)*72 + kh]);
      const bf16x8 b0 = *(const bf16x8*)(&Blds[(      m16)*72 + kh]);
      const bf16x8 b1 = *(const bf16x8*)(&Blds[(16 + m16)*72 + kh]);
      const bf16x8 b2 = *(const bf16x8*)(&Blds[(32 + m16)*72 + kh]);
      const bf16x8 b3 = *(const bf16x8*)(&Blds[(48 + m16)*72 + kh]);
      acc0 = __builtin_amdgcn_mfma_f32_16x16x32_bf16(a, b0, acc0, 0, 0, 0);
      acc1 = __builtin_amdgcn_mfma_f32_16x16x32_bf16(a, b1, acc1, 0, 0, 0);
      acc2 = __builtin_amdgcn_mfma_f32_16x16x32_bf16(a, b2, acc2, 0, 0, 0);
      acc3 = __builtin_amdgcn_mfma_f32_16x16x32_bf16(a, b3, acc3, 0, 0, 0);
    }
    __syncthreads();
  }
  // epilogue: C/D layout col=m16 -> c, row=quad*4+r -> t-local (within wave's 16)
  const int t = t0 + wave*16 + quad*4;
  if (t < TDATA) {
    float* o = outp + t;
    *(float4*)(o + (size_t)(     m16)*TDATA) = *(float4*)&acc0;
    *(float4*)(o + (size_t)(16 + m16)*TDATA) = *(float4*)&acc1;
    *(float4*)(o + (size_t)(32 + m16)*TDATA) = *(float4*)&acc2;
    if (m16 < 12)
      *(float4*)(o + (size_t)(48 + m16)*TDATA) = *(float4*)&acc3;
  }
}

// ---------------------------------------------------------------------------
// K3: 201-tap causal FIR per (var,s), with the split-K reduction fused into
//     the LDS staging: E window = in_e + P1 + P2 + P3, I window = in_i.
// ---------------------------------------------------------------------------
__device__ __forceinline__ int swz(int i) { return i + (i >> 5); }

__global__ __launch_bounds__(256) void conv_kernel(
    const float* __restrict__ in_e, const float* __restrict__ P1,
    const float* __restrict__ P2,  const float* __restrict__ P3,
    const float* __restrict__ in_i,
    const float* __restrict__ kern, float* __restrict__ syn)
{
  __shared__ float Ee[2320];
  __shared__ float Ei[2320];
  const int ch = blockIdx.y;            // var*20 + s
  const int t0 = blockIdx.x * 2048;
  const int s  = ch % SUBS;
  const size_t off = (size_t)ch * TDATA;
  for (int i = threadIdx.x; i < 2248; i += 256) {
    const int g = t0 - 200 + i;
    float e = 0.f, ii = 0.f;
    if (g >= 0 && g < TDATA) {
      e = in_e[off + g] + P1[off + g] + P2[off + g] + P3[off + g];
      ii = in_i[off + g];
    }
    Ee[swz(i)] = e;
    Ei[swz(i)] = ii;
  }
  __syncthreads();
  const float* ke = kern + (size_t)(s*2    ) * TAPS;
  const float* ki = kern + (size_t)(s*2 + 1) * TAPS;
  const int tb = threadIdx.x * 8;
  float acc[8] = {0.f,0.f,0.f,0.f,0.f,0.f,0.f,0.f};
  float we[8], wi[8];
#pragma unroll
  for (int j = 0; j < 8; ++j) {
    we[j] = Ee[swz(tb + 200 + j)];
    wi[j] = Ei[swz(tb + 200 + j)];
  }
#pragma unroll 8
  for (int m = 0; m < TAPS; ++m) {
    const float k0 = ke[m];
    const float k1 = ki[m];
#pragma unroll
    for (int j = 0; j < 8; ++j)
      acc[j] = fmaf(we[j], k0, fmaf(wi[j], k1, acc[j]));
    if (m < TAPS - 1) {
#pragma unroll
      for (int j = 7; j > 0; --j) { we[j] = we[j-1]; wi[j] = wi[j-1]; }
      we[0] = Ee[swz(tb + 199 - m)];
      wi[0] = Ei[swz(tb + 199 - m)];
    }
  }
  const int t = t0 + tb;
  if (t < TDATA) {
    float* o = syn + off + t;
    *(float4*)(o    ) = make_float4(acc[0], acc[1], acc[2], acc[3]);
    *(float4*)(o + 4) = make_float4(acc[4], acc[5], acc[6], acc[7]);
  }
}

// ---------------------------------------------------------------------------
// K4: tanh tree combine -> V outputs
// ---------------------------------------------------------------------------
__global__ __launch_bounds__(256) void tree_kernel(
    const float* __restrict__ syn, const float* __restrict__ W_sub,
    const float* __restrict__ V_o, float* __restrict__ out)
{
  const int t = blockIdx.x * 256 + threadIdx.x;
  const int var = blockIdx.y;
  if (t >= TDATA) return;
  const float* sp = syn + (size_t)var * SUBS * TDATA + t;
  float so[SUBS];
#pragma unroll
  for (int s = SUBS - 1; s >= 0; --s) {
    float val = sp[(size_t)s * TDATA];
    const int c1 = 2*s + 1, c2 = 2*s + 2;
    if (c1 < SUBS) val += so[c1] * W_sub[c1];
    if (c2 < SUBS) val += so[c2] * W_sub[c2];
    so[s] = fast_tanh(val);
  }
  out[(size_t)var * TDATA + t] = so[0] * W_sub[0] + V_o[0];
}

extern "C" void kernel_launch(void* const* d_in, const int* in_sizes, int n_in,
                              void* d_out, int out_size, void* d_ws, size_t ws_size,
                              hipStream_t stream) {
  const float* S_e     = (const float*)d_in[0];
  const float* S_i     = (const float*)d_in[1];
  const float* u       = (const float*)d_in[2];
  const float* v       = (const float*)d_in[3];
  const float* W_syn   = (const float*)d_in[4];
  const float* Tau_syn = (const float*)d_in[5];
  const float* Delta   = (const float*)d_in[6];
  const float* W_sub   = (const float*)d_in[7];
  const float* V_o     = (const float*)d_in[8];
  const float* C_log   = (const float*)d_in[10];   // d_in[9] = Theta, unused
  float* out = (float*)d_out;
  char* ws = (char*)d_ws;
  unsigned short* wge = (unsigned short*)(ws + WGE_OFF);
  unsigned short* wgi = (unsigned short*)(ws + WGI_OFF);
  float* kern = (float*)(ws + KERN_OFF);
  float* in_e = (float*)(ws + INE_OFF);
  float* in_i = (float*)(ws + INI_OFF);
  float* P1   = (float*)(ws + P1_OFF);
  float* P2   = (float*)(ws + P2_OFF);
  float* P3   = (float*)(ws + P3_OFF);
  float* syn  = (float*)(ws + SYN_OFF);

  prep_kernel<<<dim3(11), dim3(256), 0, stream>>>(u, v, C_log, W_syn, Tau_syn,
                                                  Delta, out, wge, wgi, kern);
  gemm_kernel<<<dim3(157, 5), dim3(512), 0, stream>>>(
      S_e, S_i, wge, wgi, in_e, in_i, P1, P2, P3);
  conv_kernel<<<dim3(10, 60), dim3(256), 0, stream>>>(in_e, P1, P2, P3, in_i,
                                                      kern, syn);
  tree_kernel<<<dim3(79, 3), dim3(256), 0, stream>>>(syn, W_sub, V_o, out);
}